// Round 12
// baseline (178.758 us; speedup 1.0000x reference)
//
#include <hip/hip_runtime.h>
#include <stdint.h>

// Problem constants
#define B_   8
#define S_   2047
#define L_   2048      // S+1 (CLS prepended)
#define H_   256       // HIDDEN
#define NH_  8
#define HD_  32
#define V_   32001     // VOCAB+1
#define NCH_ 128       // t-chunks per b
#define TCH_ 16        // t per chunk (NCH_*TCH_ == L_)

__device__ __forceinline__ float foldx(float a, int off) {
    return a + __shfl_xor(a, off, 64);
}
__device__ __forceinline__ float sel8(const float a[8], int j) {
    float v = a[0];
    v = (j == 1) ? a[1] : v;
    v = (j == 2) ? a[2] : v;
    v = (j == 3) ? a[3] : v;
    v = (j == 4) ? a[4] : v;
    v = (j == 5) ? a[5] : v;
    v = (j == 6) ? a[6] : v;
    v = (j == 7) ? a[7] : v;
    return v;
}

// ---------------------------------------------------------------------------
// K0 (grid 8, block per head n): y0 = emb[2]+pe[0]; q0[k] = wq[n,k,:]·y0;
// qk[n][h] = (sum_k q0[k]*wk[n,k,h]) / sqrt(32).  (r9 verbatim)
// ---------------------------------------------------------------------------
__global__ __launch_bounds__(256) void k0_prep(const float* __restrict__ emb,
                                               const float* __restrict__ wq,
                                               const float* __restrict__ wk,
                                               float* __restrict__ qk) {
    __shared__ float y0_l[H_];
    __shared__ float q0p[HD_][8];
    __shared__ float q0_l[HD_];
    int n = blockIdx.x, tid = threadIdx.x;
    float v = emb[2 * H_ + tid] + ((tid & 1) ? 1.0f : 0.0f);  // pe[0]: sin0/cos0
    y0_l[tid] = v;
    __syncthreads();
    {
        int k = tid >> 3, part = tid & 7;
        const float* w = wq + (n * HD_ + k) * H_ + part * 32;
        const float* yy = y0_l + part * 32;
        float acc = 0.f;
#pragma unroll
        for (int j = 0; j < 32; ++j) acc += w[j] * yy[j];
        q0p[k][part] = acc;
    }
    __syncthreads();
    if (tid < HD_) {
        float s = 0.f;
#pragma unroll
        for (int j = 0; j < 8; ++j) s += q0p[tid][j];
        q0_l[tid] = s;
    }
    __syncthreads();
    float acc = 0.f;
    for (int k = 0; k < HD_; ++k)
        acc += q0_l[k] * wk[(n * HD_ + k) * H_ + tid];
    qk[n * H_ + tid] = acc * 0.17677669529663687f;  // 1/sqrt(32)
}

// ---------------------------------------------------------------------------
// KA (grid 1024 = b*128+c, 4 waves x 4 t): fused scores + ybar contribution.
// r9 body verbatim (reg acc, 4-buffer LDS reduce, VGPR 56, 4 blocks/CU).
// TAIL CHANGED: plain coalesced psum/esum stores — NO atomics, NO LLC-direct.
// (r9/r11's 2-4M device atomicAdds into 64KB obar were the hidden ~50us:
// ~1 op/cycle/LLC-channel serialization. Kernel boundary gives coherence.)
// ---------------------------------------------------------------------------
__global__ __launch_bounds__(256, 4) void kA_scores(const int* __restrict__ x,
                                                    const float* __restrict__ emb,
                                                    const float* __restrict__ qk,
                                                    float* __restrict__ psum,
                                                    float* __restrict__ esum) {
    int bid = blockIdx.x, tid = threadIdx.x;
    int b = bid >> 7, c = bid & 127;
    int lane = tid & 63, w = tid >> 6;
    int h0 = lane * 4;
    int t0 = c * TCH_ + w * 4;

    __shared__ float red[4][2056];   // 32.9 KB: [wave][n*H+h] + es @2048

    float4 qr[NH_];
#pragma unroll
    for (int n = 0; n < NH_; ++n)
        qr[n] = *(const float4*)(qk + n * H_ + h0);

    int toks[4];
#pragma unroll
    for (int i = 0; i < 4; ++i) {
        int t = t0 + i;
        toks[i] = (t == 0) ? 2 : x[b * S_ + t - 1];
    }
    const float cdiv = 0.07195578414202881f;  // ln(10000)/128
    float div0 = __expf(-(float)(lane * 2) * cdiv);
    float div1 = __expf(-(float)(lane * 2 + 1) * cdiv);

    float4 acc[NH_];
    float es[NH_];
#pragma unroll
    for (int n = 0; n < NH_; ++n) {
        acc[n] = make_float4(0.f, 0.f, 0.f, 0.f);
        es[n] = 0.f;
    }

#pragma unroll
    for (int i = 0; i < 4; ++i) {
        int t = t0 + i;
        float4 ev = *(const float4*)(emb + (size_t)toks[i] * H_ + h0);
        float a0 = (float)t * div0, a1 = (float)t * div1;
        float4 y4;
        y4.x = ev.x + __sinf(a0); y4.y = ev.y + __cosf(a0);
        y4.z = ev.z + __sinf(a1); y4.w = ev.w + __cosf(a1);

        float a[NH_];
#pragma unroll
        for (int n = 0; n < NH_; ++n)
            a[n] = qr[n].x * y4.x + qr[n].y * y4.y + qr[n].z * y4.z + qr[n].w * y4.w;

        float m4[4];
#pragma unroll
        for (int k = 0; k < 4; ++k) {
            float lo = foldx(a[k], 32), hi = foldx(a[k + 4], 32);
            m4[k] = (lane & 32) ? hi : lo;
        }
        float m2[2];
#pragma unroll
        for (int k = 0; k < 2; ++k) {
            float lo = foldx(m4[k], 16), hi = foldx(m4[k + 2], 16);
            m2[k] = (lane & 16) ? hi : lo;
        }
        float lo = foldx(m2[0], 8), hi = foldx(m2[1], 8);
        float m1 = (lane & 8) ? hi : lo;
        m1 = foldx(m1, 4); m1 = foldx(m1, 2); m1 = foldx(m1, 1);
        float e = __expf(m1);  // lane n*8 holds head n's score

#pragma unroll
        for (int n = 0; n < NH_; ++n) {
            float en = __shfl(e, n * 8, 64);
            acc[n].x += en * y4.x; acc[n].y += en * y4.y;
            acc[n].z += en * y4.z; acc[n].w += en * y4.w;
            es[n] += en;
        }
    }

#pragma unroll
    for (int n = 0; n < NH_; ++n)
        *(float4*)&red[w][n * H_ + h0] = acc[n];
    if (lane < NH_) red[w][2048 + lane] = sel8(es, lane);
    __syncthreads();

    // plain coalesced stores (distinct addresses, fire-and-forget)
#pragma unroll
    for (int jj = 0; jj < (NH_ * H_) / 256; ++jj) {
        int j = jj * 256 + tid;
        psum[(size_t)bid * (NH_ * H_) + j] =
            red[0][j] + red[1][j] + red[2][j] + red[3][j];
    }
    if (tid < NH_)
        esum[bid * NH_ + tid] =
            red[0][2048 + tid] + red[1][2048 + tid]
          + red[2][2048 + tid] + red[3][2048 + tid];
}

// ---------------------------------------------------------------------------
// KR (grid 64 = b*8+jg): reduce psum over the 128 chunks -> obar[b][j].
// Coalesced cached loads: 256 consecutive floats per iteration per block.
// Block (b, jg=0) also reduces esum -> ebar[b][n].
// ---------------------------------------------------------------------------
__global__ __launch_bounds__(256) void kR_reduce(const float* __restrict__ psum,
                                                 const float* __restrict__ esum,
                                                 float* __restrict__ obar,
                                                 float* __restrict__ ebar) {
    int bid = blockIdx.x, tid = threadIdx.x;
    int b = bid >> 3, jg = bid & 7;
    int j = jg * 256 + tid;
    float s = 0.f;
#pragma unroll 8
    for (int c = 0; c < NCH_; ++c)
        s += psum[(size_t)(b * NCH_ + c) * (NH_ * H_) + j];
    obar[b * (NH_ * H_) + j] = s;
    if (jg == 0 && tid < NH_) {
        float e = 0.f;
#pragma unroll 8
        for (int c = 0; c < NCH_; ++c)
            e += esum[(b * NCH_ + c) * NH_ + tid];
        ebar[b * NH_ + tid] = e;
    }
}

// ---------------------------------------------------------------------------
// KB (grid 8 = b): ybar = obar/ebar -> wv -> wo -> z = . + 2*y0  (r9 verbatim,
// ebar now plain)
// ---------------------------------------------------------------------------
__global__ __launch_bounds__(256) void kB_proj(const float* __restrict__ emb,
                                               const float* __restrict__ obar,
                                               const float* __restrict__ ebar,
                                               const float* __restrict__ wv,
                                               const float* __restrict__ wo,
                                               float* __restrict__ z) {
    int b = blockIdx.x, tid = threadIdx.x;
    __shared__ float ybar_l[NH_ * H_];   // 8 KB
    __shared__ float o_l[NH_ * HD_];
    __shared__ float sB[NH_];
    if (tid < NH_) sB[tid] = 1.0f / ebar[b * NH_ + tid];
    __syncthreads();
    for (int i = tid; i < NH_ * H_; i += 256)
        ybar_l[i] = obar[b * (NH_ * H_) + i] * sB[i >> 8];
    __syncthreads();
    {   // wv: thread tid = n*32+k computes o[tid]
        int n = tid >> 5;
        const float* wrow = wv + (size_t)tid * H_;
        const float* yy = ybar_l + n * H_;
        float s = 0.f;
#pragma unroll 16
        for (int j4 = 0; j4 < H_ / 4; ++j4) {
            float4 w4 = *(const float4*)(wrow + j4 * 4);
            s += w4.x * yy[j4 * 4] + w4.y * yy[j4 * 4 + 1]
               + w4.z * yy[j4 * 4 + 2] + w4.w * yy[j4 * 4 + 3];
        }
        o_l[tid] = s;
    }
    __syncthreads();
    {   // wo + double residual
        float y0v = emb[2 * H_ + tid] + ((tid & 1) ? 1.0f : 0.0f);
        const float* wrow = wo + (size_t)tid * (NH_ * HD_);
        float s = 0.f;
#pragma unroll 16
        for (int j4 = 0; j4 < (NH_ * HD_) / 4; ++j4) {
            float4 w4 = *(const float4*)(wrow + j4 * 4);
            s += w4.x * o_l[j4 * 4] + w4.y * o_l[j4 * 4 + 1]
               + w4.z * o_l[j4 * 4 + 2] + w4.w * o_l[j4 * 4 + 3];
        }
        z[b * H_ + tid] = s + 2.0f * y0v;
    }
}

// ---------------------------------------------------------------------------
// KC (grid 1001, 32 vocab rows each): out[b,v] = z·wu[v]. z staged in padded
// LDS; 2 passes of 16 rows.  (r9 verbatim)
// ---------------------------------------------------------------------------
__global__ __launch_bounds__(256, 4) void kC_out(const float* __restrict__ z,
                                                 const float* __restrict__ wu,
                                                 float* __restrict__ out) {
    int bid = blockIdx.x, tid = threadIdx.x;
    int lane = tid & 63, w = tid >> 6;
    int m = lane & 15, g = lane >> 4;
    int base = bid * 32;

    __shared__ float zs[2560];       // [b*320 + (h>>4)*20 + (h&15)]
    __shared__ float sm_out[B_ * 33];
    for (int i = tid; i < B_ * H_; i += 256) {
        int bb = i >> 8, h = i & 255;
        zs[bb * 320 + (h >> 4) * 20 + (h & 15)] = z[i];
    }
    __syncthreads();

#pragma unroll
    for (int pass = 0; pass < 2; ++pass) {
        int rl = pass * 16 + w * 4 + g;
        int v = base + rl;
        int vc = (v < V_) ? v : (V_ - 1);
        const float* wr = wu + (size_t)vc * H_ + m * 16;
        float4 w0 = *(const float4*)(wr);
        float4 w1 = *(const float4*)(wr + 4);
        float4 w2 = *(const float4*)(wr + 8);
        float4 w3 = *(const float4*)(wr + 12);
        float acc[B_];
#pragma unroll
        for (int bb = 0; bb < B_; ++bb) {
            const float* zb = zs + bb * 320 + m * 20;
            float4 z0 = *(const float4*)(zb);
            float4 z1 = *(const float4*)(zb + 4);
            float4 z2 = *(const float4*)(zb + 8);
            float4 z3 = *(const float4*)(zb + 12);
            acc[bb] = z0.x * w0.x + z0.y * w0.y + z0.z * w0.z + z0.w * w0.w
                    + z1.x * w1.x + z1.y * w1.y + z1.z * w1.z + z1.w * w1.w
                    + z2.x * w2.x + z2.y * w2.y + z2.z * w2.z + z2.w * w2.w
                    + z3.x * w3.x + z3.y * w3.y + z3.z * w3.z + z3.w * w3.w;
        }
#pragma unroll
        for (int off = 1; off <= 8; off <<= 1) {
#pragma unroll
            for (int bb = 0; bb < B_; ++bb) acc[bb] += __shfl_xor(acc[bb], off, 64);
        }
        if (m < B_) sm_out[m * 33 + rl] = sel8(acc, m);
    }
    __syncthreads();
    {
        int bb = tid >> 5, vl = tid & 31, vv = base + vl;
        if (vv < V_) out[bb * V_ + vv] = sm_out[bb * 33 + vl];
    }
}

// ---------------------------------------------------------------------------
extern "C" void kernel_launch(void* const* d_in, const int* in_sizes, int n_in,
                              void* d_out, int out_size, void* d_ws, size_t ws_size,
                              hipStream_t stream) {
    const int*   x   = (const int*)d_in[0];
    const float* emb = (const float*)d_in[1];
    const float* wq  = (const float*)d_in[2];
    const float* wk  = (const float*)d_in[3];
    const float* wv  = (const float*)d_in[4];
    const float* wo  = (const float*)d_in[5];
    const float* wu  = (const float*)d_in[6];
    float*       out = (float*)d_out;

    // ws layout (floats), ~8.5 MiB:
    // qk[2048] | z[2048] | obar[8*2048] | ebar[64] | esum[1024*8]
    // | psum[1024*2048]
    // No memset needed: every word is fully overwritten each iteration.
    float* qk   = (float*)d_ws;
    float* z    = qk + NH_ * H_;
    float* obar = z + B_ * H_;
    float* ebar = obar + B_ * NH_ * H_;
    float* esum = ebar + B_ * NH_;
    float* psum = esum + 1024 * NH_;

    k0_prep  <<<8,    256, 0, stream>>>(emb, wq, wk, qk);
    kA_scores<<<1024, 256, 0, stream>>>(x, emb, qk, psum, esum);
    kR_reduce<<<64,   256, 0, stream>>>(psum, esum, obar, ebar);
    kB_proj  <<<8,    256, 0, stream>>>(emb, obar, ebar, wv, wo, z);
    kC_out   <<<1001, 256, 0, stream>>>(z, wu, out);
}

// Round 13
// 169.844 us; speedup vs baseline: 1.0525x; 1.0525x over previous
//
#include <hip/hip_runtime.h>
#include <stdint.h>

// Problem constants
#define B_   8
#define S_   2047
#define L_   2048      // S+1 (CLS prepended)
#define H_   256       // HIDDEN
#define NH_  8
#define HD_  32
#define V_   32001     // VOCAB+1
#define GRID_ 2048     // 8 blocks/CU x 256 CU -> co-resident
#define BAR_STRIDE_ 2048   // u32 per barrier region (8 KB)

// ---------------------------------------------------------------------------
// LLC-direct (coherent) access via relaxed agent-scope atomics (sc0 sc1 on
// gfx950 -> bypass L1/XCD-L2). Proven correct rounds 4-12 for cross-block
// data inside a single kernel. Read-only inputs use plain cached loads.
// ---------------------------------------------------------------------------
__device__ __forceinline__ void ast(float* p, float v) {
    __hip_atomic_store((unsigned int*)p, __float_as_uint(v),
                       __ATOMIC_RELAXED, __HIP_MEMORY_SCOPE_AGENT);
}
__device__ __forceinline__ float ald(const float* p) {
    return __uint_as_float(__hip_atomic_load((const unsigned int*)p,
                           __ATOMIC_RELAXED, __HIP_MEMORY_SCOPE_AGENT));
}
__device__ __forceinline__ unsigned aadd(unsigned* p) {
    return __hip_atomic_fetch_add(p, 1u, __ATOMIC_RELAXED, __HIP_MEMORY_SCOPE_AGENT);
}
__device__ __forceinline__ unsigned aldu(const unsigned* p) {
    return __hip_atomic_load(p, __ATOMIC_RELAXED, __HIP_MEMORY_SCOPE_AGENT);
}
__device__ __forceinline__ void vdrain() {
    asm volatile("s_waitcnt vmcnt(0)" ::: "memory");
}
__device__ __forceinline__ float foldx(float a, int off) {
    return a + __shfl_xor(a, off, 64);
}

// ---------------------------------------------------------------------------
// Contention-free grid barrier (r6-proven design, scaled to 2048 blocks):
// 32 subgroups x 64 blocks. Arrival: sub counter (64B apart) -> master;
// release: 32 separate flag lines, 64 pollers each with s_sleep.
// Layout per region (u32): [0]=master | [16+i*16]=sub_i | [528+i*16]=rel_i.
// ---------------------------------------------------------------------------
__device__ __forceinline__ void gsync(unsigned int* bp, int bid) {
    __syncthreads();
    if (threadIdx.x == 0) {
        int sg = bid & 31;
        unsigned int* sub = bp + 16 + sg * 16;
        unsigned int* rel = bp + 528 + sg * 16;
        unsigned int prev = aadd(sub);
        if (prev == (GRID_ / 32) - 1) {            // last of 64-block subgroup
            unsigned int m = aadd(bp);
            if (m == 31u) {
                for (int i = 0; i < 32; ++i)
                    __hip_atomic_store(bp + 528 + i * 16, 1u,
                                       __ATOMIC_RELAXED, __HIP_MEMORY_SCOPE_AGENT);
            }
        }
        while (aldu(rel) == 0u) __builtin_amdgcn_s_sleep(2);
    }
    __syncthreads();
}

// ---------------------------------------------------------------------------
// Mega kernel v2 ("occ8"): 5 phases, 4 barriers, 2048 blocks, 8 blocks/CU.
// The A phase is head-split to cut VGPR below the 64-reg ceiling of 32
// waves/CU (r8's 56-VGPR body carried acc[8]x4 = 32 regs; here each wave
// accumulates only 2 heads, sharing y4/e through LDS).
//   P0 (blocks 0..7):  qk prep -> qk (ast)
//   A  (all 2048):     chunk = (b, c) of 8 t; per wave: 2 t scores (17-fold)
//                      -> y4,e to LDS -> wave w accumulates heads {2w,2w+1}
//                      over all 8 t -> psum[bid][n][h] (ast), esum (lane 0)
//   R  (all 2048):     (b, jg): reduce psum over 256 chunks for 8 j-columns
//                      -> obar; jg==0 blocks reduce esum -> ebar
//   B  (blocks 0..7):  ybar = obar/ebar -> wv -> wo -> z (+2*y0) (ast)
//   C  (blocks < 2001): out[b, bid*16 .. +16] = z·wu (z staged in padded LDS)
// LDS 16.8 KB <= 20 KB cap; target VGPR ~40-50 <= 64 -> 8 blocks/CU.
// ---------------------------------------------------------------------------
__global__ __launch_bounds__(256, 8) void mega(const int* __restrict__ x,
                                               const float* __restrict__ emb,
                                               const float* __restrict__ wq,
                                               const float* __restrict__ wk,
                                               const float* __restrict__ wv,
                                               const float* __restrict__ wo,
                                               const float* __restrict__ wu,
                                               float* __restrict__ out,
                                               float* __restrict__ qk,
                                               float* __restrict__ z,
                                               float* __restrict__ obar,
                                               float* __restrict__ ebar,
                                               float* __restrict__ esum,
                                               float* __restrict__ psum,
                                               unsigned int* __restrict__ bars) {
    int bid = blockIdx.x, tid = threadIdx.x;
    int lane = tid & 63, w = tid >> 6;

    __shared__ float sm[4200];   // 16.8 KB, phase-aliased

    // ---- P0: qk prep (blocks 0..7) ----
    if (bid < NH_) {
        int n = bid;
        float* y0l = sm;          // [256]
        float* q0p = sm + 256;    // [256] = [k*8+p]
        float* q0l = sm + 512;    // [32]
        float v = emb[2 * H_ + tid] + ((tid & 1) ? 1.0f : 0.0f);  // pe[0]
        y0l[tid] = v;
        __syncthreads();
        {
            int k = tid >> 3, part = tid & 7;
            const float* wr = wq + (n * HD_ + k) * H_ + part * 32;
            const float* yy = y0l + part * 32;
            float acc = 0.f;
#pragma unroll
            for (int j = 0; j < 32; ++j) acc += wr[j] * yy[j];
            q0p[k * 8 + part] = acc;
        }
        __syncthreads();
        if (tid < HD_) {
            float s = 0.f;
#pragma unroll
            for (int j = 0; j < 8; ++j) s += q0p[tid * 8 + j];
            q0l[tid] = s;
        }
        __syncthreads();
        float acc = 0.f;
        for (int k = 0; k < HD_; ++k)
            acc += q0l[k] * wk[(n * HD_ + k) * H_ + tid];
        ast(qk + n * H_ + tid, acc * 0.17677669529663687f);  // 1/sqrt(32)
    }
    vdrain();
    gsync(bars + 0 * BAR_STRIDE_, bid);

    // ---- A: head-split fused scores (all 2048 blocks, 8-t chunks) ----
    {
        int b = bid >> 8, c = bid & 255;
        int h0 = lane * 4;
        float* qk_l = sm;          // [2048]
        float* y4_l = sm + 2048;   // [2048] = [tl*256 + h]
        float* e_l  = sm + 4096;   // [64]   = [tl*8 + n]

        for (int i = tid; i < NH_ * H_; i += 256) qk_l[i] = ald(qk + i);
        __syncthreads();

        const float cdiv = 0.07195578414202881f;  // ln(10000)/128
        float div0 = __expf(-(float)(lane * 2) * cdiv);
        float div1 = __expf(-(float)(lane * 2 + 1) * cdiv);

#pragma unroll
        for (int it = 0; it < 2; ++it) {
            int tl = w * 2 + it;
            int t = c * 8 + tl;
            int tok = (t == 0) ? 2 : x[b * S_ + t - 1];
            float4 ev = *(const float4*)(emb + (size_t)tok * H_ + h0);
            float a0 = (float)t * div0, a1 = (float)t * div1;
            float4 y4;
            y4.x = ev.x + __sinf(a0); y4.y = ev.y + __cosf(a0);
            y4.z = ev.z + __sinf(a1); y4.w = ev.w + __cosf(a1);
            *(float4*)&y4_l[tl * 256 + h0] = y4;

            float a[NH_];
#pragma unroll
            for (int n = 0; n < NH_; ++n) {
                float4 q4 = *(const float4*)&qk_l[n * H_ + h0];
                a[n] = q4.x * y4.x + q4.y * y4.y + q4.z * y4.z + q4.w * y4.w;
            }
            float m4[4];
#pragma unroll
            for (int k = 0; k < 4; ++k) {
                float lo = foldx(a[k], 32), hi = foldx(a[k + 4], 32);
                m4[k] = (lane & 32) ? hi : lo;
            }
            float m2[2];
#pragma unroll
            for (int k = 0; k < 2; ++k) {
                float lo = foldx(m4[k], 16), hi = foldx(m4[k + 2], 16);
                m2[k] = (lane & 16) ? hi : lo;
            }
            float lo = foldx(m2[0], 8), hi = foldx(m2[1], 8);
            float m1 = (lane & 8) ? hi : lo;
            m1 = foldx(m1, 4); m1 = foldx(m1, 2); m1 = foldx(m1, 1);
            float e = __expf(m1);  // every lane in 8-group holds its head's e
            if ((lane & 7) == 0) e_l[tl * 8 + (lane >> 3)] = e;
        }
        __syncthreads();

        // wave w accumulates heads n0=2w, n1=2w+1 over all 8 t
        int n0 = w * 2, n1 = n0 + 1;
        float4 A0 = make_float4(0.f, 0.f, 0.f, 0.f);
        float4 A1 = make_float4(0.f, 0.f, 0.f, 0.f);
        float es0 = 0.f, es1 = 0.f;
#pragma unroll
        for (int tl = 0; tl < 8; ++tl) {
            float4 yv = *(const float4*)&y4_l[tl * 256 + h0];
            float e0 = e_l[tl * 8 + n0];
            float e1 = e_l[tl * 8 + n1];
            A0.x += e0 * yv.x; A0.y += e0 * yv.y; A0.z += e0 * yv.z; A0.w += e0 * yv.w;
            A1.x += e1 * yv.x; A1.y += e1 * yv.y; A1.z += e1 * yv.z; A1.w += e1 * yv.w;
            es0 += e0; es1 += e1;
        }
        float* p0 = psum + (size_t)bid * (NH_ * H_) + n0 * H_ + h0;
        ast(p0 + 0, A0.x); ast(p0 + 1, A0.y); ast(p0 + 2, A0.z); ast(p0 + 3, A0.w);
        float* p1 = psum + (size_t)bid * (NH_ * H_) + n1 * H_ + h0;
        ast(p1 + 0, A1.x); ast(p1 + 1, A1.y); ast(p1 + 2, A1.z); ast(p1 + 3, A1.w);
        if (lane == 0) {   // es is lane-uniform: no reduce needed
            ast(esum + bid * NH_ + n0, es0);
            ast(esum + bid * NH_ + n1, es1);
        }
    }
    vdrain();
    gsync(bars + 1 * BAR_STRIDE_, bid);

    // ---- R: parallel psum reduce -> obar / ebar (all 2048 blocks) ----
    {
        int b = bid >> 8, jg = bid & 255;
        int jl = tid & 7, c8 = tid >> 3;     // 32 chunk-groups of 8
        int j = jg * 8 + jl;
        float s = 0.f;
#pragma unroll
        for (int i = 0; i < 8; ++i)
            s += ald(psum + (size_t)(b * 256 + c8 * 8 + i) * (NH_ * H_) + j);
        sm[jl * 32 + c8] = s;
        __syncthreads();
        if (tid < 8) {
            float t = 0.f;
#pragma unroll
            for (int g = 0; g < 32; ++g) t += sm[tid * 32 + g];
            ast(obar + b * (NH_ * H_) + jg * 8 + tid, t);
        }
        if (jg == 0) {       // jg uniform per block: safe divergence
            int n = tid & 7;
            float e = 0.f;
#pragma unroll
            for (int i = 0; i < 8; ++i)
                e += ald(esum + (b * 256 + c8 * 8 + i) * NH_ + n);
            sm[256 + n * 32 + c8] = e;
            __syncthreads();
            if (tid < 8) {
                float t = 0.f;
#pragma unroll
                for (int g = 0; g < 32; ++g) t += sm[256 + tid * 32 + g];
                ast(ebar + b * NH_ + tid, t);
            }
        }
    }
    vdrain();
    gsync(bars + 2 * BAR_STRIDE_, bid);

    // ---- B: normalize -> wv -> wo -> z (blocks 0..7) ----
    if (bid < B_) {
        int b = bid;
        float* ybar_l = sm;            // [2048]
        float* o_l    = sm + 2048;     // [256]
        float* sB     = sm + 2304;     // [8]
        if (tid < NH_) sB[tid] = 1.0f / ald(ebar + b * NH_ + tid);
        __syncthreads();
        for (int i = tid; i < NH_ * H_; i += 256)
            ybar_l[i] = ald(obar + b * (NH_ * H_) + i) * sB[i >> 8];
        __syncthreads();
        {   // wv: thread tid = n*32+k
            int n = tid >> 5;
            const float* wrow = wv + (size_t)tid * H_;
            const float* yy = ybar_l + n * H_;
            float s = 0.f;
#pragma unroll 16
            for (int j4 = 0; j4 < H_ / 4; ++j4) {
                float4 w4 = *(const float4*)(wrow + j4 * 4);
                s += w4.x * yy[j4 * 4] + w4.y * yy[j4 * 4 + 1]
                   + w4.z * yy[j4 * 4 + 2] + w4.w * yy[j4 * 4 + 3];
            }
            o_l[tid] = s;
        }
        __syncthreads();
        {   // wo + double residual
            float y0v = emb[2 * H_ + tid] + ((tid & 1) ? 1.0f : 0.0f);
            const float* wrow = wo + (size_t)tid * (NH_ * HD_);
            float s = 0.f;
#pragma unroll 16
            for (int j4 = 0; j4 < (NH_ * HD_) / 4; ++j4) {
                float4 w4 = *(const float4*)(wrow + j4 * 4);
                s += w4.x * o_l[j4 * 4] + w4.y * o_l[j4 * 4 + 1]
                   + w4.z * o_l[j4 * 4 + 2] + w4.w * o_l[j4 * 4 + 3];
            }
            ast(z + b * H_ + tid, s + 2.0f * y0v);
        }
    }
    vdrain();
    gsync(bars + 3 * BAR_STRIDE_, bid);

    // ---- C: out = z · wu^T (blocks < 2001, 16 vocab rows, single pass) ----
    if (bid < (V_ + 15) / 16) {
        int m = lane & 15, g = lane >> 4;
        int base = bid * 16;
        float* zs = sm;                // [2560] padded [b*320+(h>>4)*20+(h&15)]
        float* sm_out = sm + 2560;     // [8*17]
        for (int i = tid; i < B_ * H_; i += 256) {
            int bb = i >> 8, h = i & 255;
            zs[bb * 320 + (h >> 4) * 20 + (h & 15)] = ald(z + i);
        }
        __syncthreads();

        int rl = w * 4 + g;            // 0..15
        int v = base + rl;
        int vc = (v < V_) ? v : (V_ - 1);
        const float* wr = wu + (size_t)vc * H_ + m * 16;
        float4 w0 = *(const float4*)(wr);
        float4 w1 = *(const float4*)(wr + 4);
        float4 w2 = *(const float4*)(wr + 8);
        float4 w3 = *(const float4*)(wr + 12);
        float acc[B_];
#pragma unroll
        for (int bb = 0; bb < B_; ++bb) {
            const float* zb = zs + bb * 320 + m * 20;
            float4 z0 = *(const float4*)(zb);
            float4 z1 = *(const float4*)(zb + 4);
            float4 z2 = *(const float4*)(zb + 8);
            float4 z3 = *(const float4*)(zb + 12);
            acc[bb] = z0.x * w0.x + z0.y * w0.y + z0.z * w0.z + z0.w * w0.w
                    + z1.x * w1.x + z1.y * w1.y + z1.z * w1.z + z1.w * w1.w
                    + z2.x * w2.x + z2.y * w2.y + z2.z * w2.z + z2.w * w2.w
                    + z3.x * w3.x + z3.y * w3.y + z3.z * w3.z + z3.w * w3.w;
        }
#pragma unroll
        for (int off = 1; off <= 8; off <<= 1) {
#pragma unroll
            for (int bb = 0; bb < B_; ++bb) acc[bb] += __shfl_xor(acc[bb], off, 64);
        }
        // lane m<8 holds acc[m]'s reduced value for row rl? No: after full
        // 1..8 fold, acc[bb] is summed over each 16-lane group; lane m of the
        // group that owns row rl writes out[bb]. Use group-lane m as selector.
        if (m < B_) {
            float v8 = acc[0];
            v8 = (m == 1) ? acc[1] : v8;
            v8 = (m == 2) ? acc[2] : v8;
            v8 = (m == 3) ? acc[3] : v8;
            v8 = (m == 4) ? acc[4] : v8;
            v8 = (m == 5) ? acc[5] : v8;
            v8 = (m == 6) ? acc[6] : v8;
            v8 = (m == 7) ? acc[7] : v8;
            sm_out[m * 17 + rl] = v8;
        }
        __syncthreads();
        if (tid < B_ * 16) {
            int bb = tid >> 4, vl = tid & 15, vv = base + vl;
            if (vv < V_) out[bb * V_ + vv] = sm_out[bb * 17 + vl];
        }
    }
}

// ---------------------------------------------------------------------------
extern "C" void kernel_launch(void* const* d_in, const int* in_sizes, int n_in,
                              void* d_out, int out_size, void* d_ws, size_t ws_size,
                              hipStream_t stream) {
    const int*   x   = (const int*)d_in[0];
    const float* emb = (const float*)d_in[1];
    const float* wq  = (const float*)d_in[2];
    const float* wk  = (const float*)d_in[3];
    const float* wv  = (const float*)d_in[4];
    const float* wo  = (const float*)d_in[5];
    const float* wu  = (const float*)d_in[6];
    float*       out = (float*)d_out;

    // ws layout (floats unless noted), ~16.2 MiB:
    // qk[2048] | z[2048] | obar[8*2048] | ebar[64] | esum[2048*8]
    // | psum[2048*2048] | bars[4*2048 u32]
    float* qk   = (float*)d_ws;
    float* z    = qk + NH_ * H_;
    float* obar = z + B_ * H_;
    float* ebar = obar + B_ * NH_ * H_;
    float* esum = ebar + B_ * NH_;
    float* psum = esum + (size_t)GRID_ * NH_;
    unsigned int* bars = (unsigned int*)(psum + (size_t)GRID_ * NH_ * H_);

    // Zero the barrier counters (workspace is poisoned each iteration).
    hipMemsetAsync(bars, 0, 4 * BAR_STRIDE_ * sizeof(unsigned int), stream);

    mega<<<GRID_, 256, 0, stream>>>(x, emb, wq, wk, wv, wo, wu, out,
                                    qk, z, obar, ebar, esum, psum, bars);
}

// Round 14
// 150.106 us; speedup vs baseline: 1.1909x; 1.1315x over previous
//
#include <hip/hip_runtime.h>
#include <stdint.h>

// Problem constants
#define B_   8
#define S_   2047
#define L_   2048      // S+1 (CLS prepended)
#define H_   256       // HIDDEN
#define NH_  8
#define HD_  32
#define V_   32001     // VOCAB+1
#define NCH_ 128       // t-chunks per b
#define TCH_ 16        // t per chunk
#define GRID_ 1024     // 4 blocks/CU x 256 CU -> co-resident (proven)
#define BAR_STRIDE_ 2048   // u32 per barrier region (8 KB)
#define YP_  260       // padded row stride (bank-conflict-free)

// ---------------------------------------------------------------------------
// LLC-direct (coherent) access via relaxed agent-scope atomics (sc0 sc1 on
// gfx950 -> bypass L1/XCD-L2). Proven correct rounds 4-13 for cross-phase
// data inside a single kernel. Read-only inputs use plain cached loads.
// ---------------------------------------------------------------------------
__device__ __forceinline__ void ast(float* p, float v) {
    __hip_atomic_store((unsigned int*)p, __float_as_uint(v),
                       __ATOMIC_RELAXED, __HIP_MEMORY_SCOPE_AGENT);
}
__device__ __forceinline__ float ald(const float* p) {
    return __uint_as_float(__hip_atomic_load((const unsigned int*)p,
                           __ATOMIC_RELAXED, __HIP_MEMORY_SCOPE_AGENT));
}
__device__ __forceinline__ unsigned aadd(unsigned* p) {
    return __hip_atomic_fetch_add(p, 1u, __ATOMIC_RELAXED, __HIP_MEMORY_SCOPE_AGENT);
}
__device__ __forceinline__ unsigned aldu(const unsigned* p) {
    return __hip_atomic_load(p, __ATOMIC_RELAXED, __HIP_MEMORY_SCOPE_AGENT);
}
__device__ __forceinline__ void vdrain() {
    asm volatile("s_waitcnt vmcnt(0)" ::: "memory");
}
__device__ __forceinline__ float sel8(const float a[8], int j) {
    float v = a[0];
    v = (j == 1) ? a[1] : v;
    v = (j == 2) ? a[2] : v;
    v = (j == 3) ? a[3] : v;
    v = (j == 4) ? a[4] : v;
    v = (j == 5) ? a[5] : v;
    v = (j == 6) ? a[6] : v;
    v = (j == 7) ? a[7] : v;
    return v;
}

// ---------------------------------------------------------------------------
// Contention-free grid barrier (r6-proven, fence-free; data goes via ast/ald)
// 32 subgroups x 32 blocks; release via 32 separate flag lines.
// Layout per region (u32): [0]=master | [16+i*16]=sub_i | [528+i*16]=rel_i.
// ---------------------------------------------------------------------------
__device__ __forceinline__ void gsync(unsigned int* bp, int bid) {
    __syncthreads();
    if (threadIdx.x == 0) {
        int sg = bid & 31;
        unsigned int* sub = bp + 16 + sg * 16;
        unsigned int* rel = bp + 528 + sg * 16;
        unsigned int prev = aadd(sub);
        if (prev == (GRID_ / 32) - 1) {
            unsigned int m = aadd(bp);
            if (m == 31u) {
                for (int i = 0; i < 32; ++i)
                    __hip_atomic_store(bp + 528 + i * 16, 1u,
                                       __ATOMIC_RELAXED, __HIP_MEMORY_SCOPE_AGENT);
            }
        }
        while (aldu(rel) == 0u) __builtin_amdgcn_s_sleep(2);
    }
    __syncthreads();
}

// ---------------------------------------------------------------------------
// Mega v3 ("LDS-dot A"): r6 skeleton, A-phase algorithm replaced.
//   P0 (blocks 0..7):  qk prep -> qk (ast)
//   A  (all 1024, 16-t chunk):
//        stage y rows (emb[tok]+pe) into padded LDS (stride 260) +
//        qk into padded LDS; scores = per-thread 128-MAC half-dots from LDS
//        (NO shuffle fold, NO per-lane trig in inner loop) -> exp -> e_l;
//        accum: thread h: acc[n] += e[t][n]*y[t][h] from LDS -> psum (ast)
//   R  (all 1024):     (b, jg): reduce psum over 128 chunks, 16 j-cols
//                      -> obar; jg==0 also esum -> ebar
//   B  (blocks 0..7):  ybar = obar/ebar -> wv -> wo -> z (+2*y0) (ast)
//   C  (blocks <1001): out = z·wu (32 rows, 2 passes; z staged padded LDS)
// LDS 26.6 KB -> 4 blocks/CU (LDS 106 KB, VGPR ~56 under 128 cap).
// ---------------------------------------------------------------------------
__global__ __launch_bounds__(256, 4) void mega(const int* __restrict__ x,
                                               const float* __restrict__ emb,
                                               const float* __restrict__ wq,
                                               const float* __restrict__ wk,
                                               const float* __restrict__ wv,
                                               const float* __restrict__ wo,
                                               const float* __restrict__ wu,
                                               float* __restrict__ out,
                                               float* __restrict__ qk,
                                               float* __restrict__ z,
                                               float* __restrict__ obar,
                                               float* __restrict__ ebar,
                                               float* __restrict__ esum,
                                               float* __restrict__ psum,
                                               unsigned int* __restrict__ bars) {
    int bid = blockIdx.x, tid = threadIdx.x;
    int lane = tid & 63, w = tid >> 6;

    __shared__ float sm[6640];   // 26.6 KB, phase-aliased

    // ---- P0: qk prep (blocks 0..7) ----
    if (bid < NH_) {
        int n = bid;
        float* y0l = sm;          // [256]
        float* q0p = sm + 256;    // [256] = [k*8+p]
        float* q0l = sm + 512;    // [32]
        float v = emb[2 * H_ + tid] + ((tid & 1) ? 1.0f : 0.0f);  // pe[0]
        y0l[tid] = v;
        __syncthreads();
        {
            int k = tid >> 3, part = tid & 7;
            const float* wr = wq + (n * HD_ + k) * H_ + part * 32;
            const float* yy = y0l + part * 32;
            float acc = 0.f;
#pragma unroll
            for (int j = 0; j < 32; ++j) acc += wr[j] * yy[j];
            q0p[k * 8 + part] = acc;
        }
        __syncthreads();
        if (tid < HD_) {
            float s = 0.f;
#pragma unroll
            for (int j = 0; j < 8; ++j) s += q0p[tid * 8 + j];
            q0l[tid] = s;
        }
        __syncthreads();
        float acc = 0.f;
        for (int k = 0; k < HD_; ++k)
            acc += q0l[k] * wk[(n * HD_ + k) * H_ + tid];
        ast(qk + n * H_ + tid, acc * 0.17677669529663687f);  // 1/sqrt(32)
    }
    vdrain();
    gsync(bars + 0 * BAR_STRIDE_, bid);

    // ---- A: LDS-dot fused scores (all 1024 blocks, 16-t chunks) ----
    {
        int b = bid >> 7, c = bid & 127;
        int t0 = c * TCH_;
        float* y_l   = sm;                    // [16][260]
        float* qk_l  = sm + TCH_ * YP_;       // [8][260]      @4160
        float* e_l   = qk_l + NH_ * YP_;      // [16*8]        @6240
        float* part  = e_l + TCH_ * NH_;      // [256]         @6368
        // tok_l shares part[] space until dot phase? must survive staging only.
        __shared__ int tok_l[TCH_];

        if (tid < TCH_) {
            int t = t0 + tid;
            tok_l[tid] = (t == 0) ? 2 : x[b * S_ + t - 1];
        }
        // stage qk (padded stride 260)
        for (int i = tid; i < NH_ * H_; i += 256)
            qk_l[(i >> 8) * YP_ + (i & 255)] = ald(qk + i);
        __syncthreads();

        // stage y rows: iteration r loads row r coalesced (col = tid)
        const float cdiv = 0.07195578414202881f;  // ln(10000)/128
        float divc = __expf(-(float)(tid >> 1) * cdiv);
        bool isOdd = (tid & 1);
#pragma unroll 4
        for (int r = 0; r < TCH_; ++r) {
            int t = t0 + r;
            float ev = emb[(size_t)tok_l[r] * H_ + tid];
            float ang = (float)t * divc;
            float pe = isOdd ? __cosf(ang) : __sinf(ang);
            y_l[r * YP_ + tid] = ev + pe;
        }
        __syncthreads();

        // dot phase: thread = (half, t, n); 128-MAC half-dot from LDS
        {
            int half = tid >> 7, tn = tid & 127;
            int t = tn >> 3, n = tn & 7;
            const float* yr = y_l + t * YP_ + half * 128;
            const float* qr = qk_l + n * YP_ + half * 128;
            float s = 0.f;
#pragma unroll
            for (int j = 0; j < 32; ++j) {
                float4 y4 = *(const float4*)(yr + j * 4);
                float4 q4 = *(const float4*)(qr + j * 4);
                s += y4.x * q4.x + y4.y * q4.y + y4.z * q4.z + y4.w * q4.w;
            }
            part[tid] = s;
        }
        __syncthreads();
        if (tid < 128)
            e_l[tid] = __expf(part[tid] + part[128 + tid]);
        __syncthreads();

        // accum phase: thread = h; acc[n] += e[t][n] * y[t][h]
        {
            float acc[NH_] = {};
#pragma unroll
            for (int t = 0; t < TCH_; ++t) {
                float yv = y_l[t * YP_ + tid];
                float4 eA = *(const float4*)&e_l[t * 8];      // broadcast
                float4 eB = *(const float4*)&e_l[t * 8 + 4];
                acc[0] += eA.x * yv; acc[1] += eA.y * yv;
                acc[2] += eA.z * yv; acc[3] += eA.w * yv;
                acc[4] += eB.x * yv; acc[5] += eB.y * yv;
                acc[6] += eB.z * yv; acc[7] += eB.w * yv;
            }
#pragma unroll
            for (int n = 0; n < NH_; ++n)
                ast(psum + (size_t)bid * (NH_ * H_) + n * H_ + tid, acc[n]);
        }
        if (tid < NH_) {
            float s = 0.f;
#pragma unroll
            for (int t = 0; t < TCH_; ++t) s += e_l[t * 8 + tid];
            ast(esum + bid * NH_ + tid, s);
        }
    }
    vdrain();
    gsync(bars + 1 * BAR_STRIDE_, bid);

    // ---- R: parallel psum reduce -> obar / ebar (all 1024 blocks) ----
    {
        int b = bid >> 7, jg = bid & 127;
        int jl = tid & 15, cg = tid >> 4;     // 16 j-cols x 16 chunk-groups
        int j = jg * 16 + jl;
        float s = 0.f;
#pragma unroll
        for (int i = 0; i < 8; ++i)
            s += ald(psum + (size_t)(b * NCH_ + cg * 8 + i) * (NH_ * H_) + j);
        sm[cg * 16 + jl] = s;
        __syncthreads();
        if (tid < 16) {
            float t = 0.f;
#pragma unroll
            for (int g = 0; g < 16; ++g) t += sm[g * 16 + tid];
            ast(obar + b * (NH_ * H_) + jg * 16 + tid, t);
        }
        if (jg == 0) {       // jg uniform per block: safe divergence
            int n = tid & 7, cg2 = tid >> 3;  // 32 groups x 4 chunks
            float e = 0.f;
#pragma unroll
            for (int i = 0; i < 4; ++i)
                e += ald(esum + (b * NCH_ + cg2 * 4 + i) * NH_ + n);
            sm[512 + cg2 * 8 + n] = e;
            __syncthreads();
            if (tid < 8) {
                float t = 0.f;
#pragma unroll
                for (int g = 0; g < 32; ++g) t += sm[512 + g * 8 + tid];
                ast(ebar + b * NH_ + tid, t);
            }
        }
    }
    vdrain();
    gsync(bars + 2 * BAR_STRIDE_, bid);

    // ---- B: normalize -> wv -> wo -> z (blocks 0..7) ----
    if (bid < B_) {
        int b = bid;
        float* ybar_l = sm;            // [2048]
        float* o_l    = sm + 2048;     // [256]
        float* sB     = sm + 2304;     // [8]
        if (tid < NH_) sB[tid] = 1.0f / ald(ebar + b * NH_ + tid);
        __syncthreads();
        for (int i = tid; i < NH_ * H_; i += 256)
            ybar_l[i] = ald(obar + b * (NH_ * H_) + i) * sB[i >> 8];
        __syncthreads();
        {   // wv: thread tid = n*32+k
            int n = tid >> 5;
            const float* wrow = wv + (size_t)tid * H_;
            const float* yy = ybar_l + n * H_;
            float s = 0.f;
#pragma unroll 16
            for (int j4 = 0; j4 < H_ / 4; ++j4) {
                float4 w4 = *(const float4*)(wrow + j4 * 4);
                s += w4.x * yy[j4 * 4] + w4.y * yy[j4 * 4 + 1]
                   + w4.z * yy[j4 * 4 + 2] + w4.w * yy[j4 * 4 + 3];
            }
            o_l[tid] = s;
        }
        __syncthreads();
        {   // wo + double residual
            float y0v = emb[2 * H_ + tid] + ((tid & 1) ? 1.0f : 0.0f);
            const float* wrow = wo + (size_t)tid * (NH_ * HD_);
            float s = 0.f;
#pragma unroll 16
            for (int j4 = 0; j4 < (NH_ * HD_) / 4; ++j4) {
                float4 w4 = *(const float4*)(wrow + j4 * 4);
                s += w4.x * o_l[j4 * 4] + w4.y * o_l[j4 * 4 + 1]
                   + w4.z * o_l[j4 * 4 + 2] + w4.w * o_l[j4 * 4 + 3];
            }
            ast(z + b * H_ + tid, s + 2.0f * y0v);
        }
    }
    vdrain();
    gsync(bars + 3 * BAR_STRIDE_, bid);

    // ---- C: out = z · wu^T (blocks < 1001, 32 rows, 2 passes) ----
    if (bid < (V_ + 31) / 32) {
        int m = lane & 15, g = lane >> 4;
        int base = bid * 32;
        float* zs = sm;                // [2560] padded [b*320+(h>>4)*20+(h&15)]
        float* sm_out = sm + 2560;     // [8*33]
        for (int i = tid; i < B_ * H_; i += 256) {
            int bb = i >> 8, h = i & 255;
            zs[bb * 320 + (h >> 4) * 20 + (h & 15)] = ald(z + i);
        }
        __syncthreads();

#pragma unroll
        for (int pass = 0; pass < 2; ++pass) {
            int rl = pass * 16 + w * 4 + g;
            int v = base + rl;
            int vc = (v < V_) ? v : (V_ - 1);
            const float* wr = wu + (size_t)vc * H_ + m * 16;
            float4 w0 = *(const float4*)(wr);
            float4 w1 = *(const float4*)(wr + 4);
            float4 w2 = *(const float4*)(wr + 8);
            float4 w3 = *(const float4*)(wr + 12);
            float acc[B_];
#pragma unroll
            for (int bb = 0; bb < B_; ++bb) {
                const float* zb = zs + bb * 320 + m * 20;
                float4 z0 = *(const float4*)(zb);
                float4 z1 = *(const float4*)(zb + 4);
                float4 z2 = *(const float4*)(zb + 8);
                float4 z3 = *(const float4*)(zb + 12);
                acc[bb] = z0.x * w0.x + z0.y * w0.y + z0.z * w0.z + z0.w * w0.w
                        + z1.x * w1.x + z1.y * w1.y + z1.z * w1.z + z1.w * w1.w
                        + z2.x * w2.x + z2.y * w2.y + z2.z * w2.z + z2.w * w2.w
                        + z3.x * w3.x + z3.y * w3.y + z3.z * w3.z + z3.w * w3.w;
            }
#pragma unroll
            for (int off = 1; off <= 8; off <<= 1) {
#pragma unroll
                for (int bb = 0; bb < B_; ++bb)
                    acc[bb] += __shfl_xor(acc[bb], off, 64);
            }
            if (m < B_) sm_out[m * 33 + rl] = sel8(acc, m);
        }
        __syncthreads();
        {
            int bb = tid >> 5, vl = tid & 31, vv = base + vl;
            if (vv < V_) out[bb * V_ + vv] = sm_out[bb * 33 + vl];
        }
    }
}

// ---------------------------------------------------------------------------
extern "C" void kernel_launch(void* const* d_in, const int* in_sizes, int n_in,
                              void* d_out, int out_size, void* d_ws, size_t ws_size,
                              hipStream_t stream) {
    const int*   x   = (const int*)d_in[0];
    const float* emb = (const float*)d_in[1];
    const float* wq  = (const float*)d_in[2];
    const float* wk  = (const float*)d_in[3];
    const float* wv  = (const float*)d_in[4];
    const float* wo  = (const float*)d_in[5];
    const float* wu  = (const float*)d_in[6];
    float*       out = (float*)d_out;

    // ws layout (floats unless noted), ~8.6 MiB:
    // qk[2048] | z[2048] | obar[8*2048] | ebar[64] | esum[1024*8]
    // | psum[1024*2048] | bars[4*2048 u32]
    float* qk   = (float*)d_ws;
    float* z    = qk + NH_ * H_;
    float* obar = z + B_ * H_;
    float* ebar = obar + B_ * NH_ * H_;
    float* esum = ebar + B_ * NH_;
    float* psum = esum + (size_t)GRID_ * NH_;
    unsigned int* bars = (unsigned int*)(psum + (size_t)GRID_ * NH_ * H_);

    // Zero the barrier counters (workspace is poisoned each iteration).
    hipMemsetAsync(bars, 0, 4 * BAR_STRIDE_ * sizeof(unsigned int), stream);

    mega<<<GRID_, 256, 0, stream>>>(x, emb, wq, wk, wv, wo, wu, out,
                                    qk, z, obar, ebar, esum, psum, bars);
}